// Round 14
// baseline (66.839 us; speedup 1.0000x reference)
//
#include <hip/hip_runtime.h>

typedef unsigned short u16;
typedef unsigned int   u32;
typedef short s8v  __attribute__((ext_vector_type(8)));   // 8 bf16 (4 VGPR)
typedef float f16v __attribute__((ext_vector_type(16)));  // 32x32 acc
typedef unsigned int u32x4 __attribute__((ext_vector_type(4)));

#define ROWBYTES 4224                 // 4 c-chunks * (66 px * 16 B)
#define NROWS    18                   // 16 output rows + 2 halo
#define LDS_BYTES (NROWS * ROWBYTES)  // 76032 -> 2 blocks/CU

__device__ inline u16 f2bf(float f) {
    u32 u = __builtin_bit_cast(u32, f);
    u += 0x7FFFu + ((u >> 16) & 1u);   // RNE; inputs finite
    return (u16)(u >> 16);
}
__device__ inline u32 pk2(float lo, float hi) {
    return (u32)f2bf(lo) | ((u32)f2bf(hi) << 16);
}

// R12 structure at 2x thread-level parallelism: 512 thr = 8 waves, 16h tile,
// h-major page-sequential staging (each wave: one c-chunk x 9-row range,
// ~18 live floats -> fits 128-VGPR cap), ONE barrier, 2 MFMA rows per wave.
// 2 blocks/CU -> 16 waves/CU smooths the read/write duty cycle.
// Grid: 16n*16hs*4wb = 1024, XCD-swizzled.
__global__ __launch_bounds__(512, 2) void k_fused(const float* __restrict__ x,
                                                  const float* __restrict__ wgt,
                                                  const float* __restrict__ bias,
                                                  const float* __restrict__ scale_p,
                                                  float* __restrict__ out) {
    __shared__ __align__(16) char lds[LDS_BYTES];

    // bijective XCD swizzle: 8 consecutive logical blocks -> same XCD
    const int b    = ((blockIdx.x & 7) << 7) | (blockIdx.x >> 3);   // grid 1024
    const int wb   = b & 3;
    const int hs   = (b >> 2) & 15;
    const int n    = b >> 6;
    const int w0   = wb << 6;
    const int h0   = hs << 4;
    const int t    = threadIdx.x;
    const int l    = t & 63;
    const int wave = t >> 6;           // 0..7
    const int g    = l >> 5;
    const int ln   = l & 31;

    // ---- weight repack into LDS overlay: [o][c][9] f32 -> [tap][o*32+c] bf16
    {
        u16* wl = (u16*)lds;
        #pragma unroll
        for (int k = 0; k < 18; ++k) {               // 9216 = 18*512
            const int idx = t + (k << 9);
            const int tap = idx % 9;
            const int oc  = idx / 9;
            wl[tap * 1024 + oc] = f2bf(wgt[idx]);
        }
    }
    __syncthreads();

    // A frags: wt[tap][o=ln][c = q*16 + g*8 + e]
    s8v A[9][2];
    {
        const u16* wl = (const u16*)lds;
        #pragma unroll
        for (int tap = 0; tap < 9; ++tap)
            #pragma unroll
            for (int q = 0; q < 2; ++q)
                A[tap][q] = *(const s8v*)(wl + tap * 1024 + ln * 32 + q * 16 + g * 8);
    }
    const float scale = scale_p[0];
    float bias_r[16];
    #pragma unroll
    for (int rg = 0; rg < 16; ++rg) bias_r[rg] = bias[(rg & 3) + 8 * (rg >> 2) + 4 * g];
    __syncthreads();   // weight overlay free

    const float* xbase = x + ((size_t)n << 21);           // n*32*65536

    // ---- halo px (ps=0, ps=65): 144 gather threads, u32x4 writes
    if (t < 144) {
        const int cc   = t / 36;
        const int rem  = t - cc * 36;
        const int side = rem / 18;
        const int r    = rem - side * 18;
        const int hin  = h0 - 1 + r;
        const int wg   = w0 - 1 + side * 65;
        u32 q0 = 0, q1 = 0, q2 = 0, q3 = 0;
        if (hin >= 0 && hin < 256 && wg >= 0 && wg < 256) {
            const float* p = xbase + (size_t)(cc * 8) * 65536 + (size_t)hin * 256 + wg;
            q0 = pk2(p[0],      p[65536]);
            q1 = pk2(p[131072], p[196608]);
            q2 = pk2(p[262144], p[327680]);
            q3 = pk2(p[393216], p[458752]);
        }
        *(u32x4*)(lds + r * ROWBYTES + cc * 1056 + side * 1040) = u32x4{q0, q1, q2, q3};
    }

    // ---- main staging, h-major per channel-pair: wave = (c-chunk, 9-row range);
    // lane l -> px w0+l (ps=l+1). Per pair j: 9 page-sequential loads of channel
    // 2j, 9 of channel 2j+1, then 9 packed u32 LDS writes.
    {
        const int chunk = wave & 3;
        const int half  = wave >> 2;
        const int rbase = half * 9;
        const float* pc = xbase + (size_t)(chunk * 8) * 65536 + w0 + l;
        char* ldst = lds + chunk * 1056 + ((l + 1) << 4);
        #pragma unroll
        for (int j = 0; j < 4; ++j) {
            const float* p0 = pc + (size_t)(2 * j) * 65536;
            const float* p1 = p0 + 65536;
            float a[9], c2[9];
            #pragma unroll
            for (int k = 0; k < 9; ++k) {                 // channel 2j: 9 seq rows
                const int hin = h0 - 1 + rbase + k;
                const int hcl = hin < 0 ? 0 : (hin > 255 ? 255 : hin);
                a[k] = p0[(size_t)hcl * 256];
            }
            #pragma unroll
            for (int k = 0; k < 9; ++k) {                 // channel 2j+1: 9 seq rows
                const int hin = h0 - 1 + rbase + k;
                const int hcl = hin < 0 ? 0 : (hin > 255 ? 255 : hin);
                c2[k] = p1[(size_t)hcl * 256];
            }
            #pragma unroll
            for (int k = 0; k < 9; ++k) {
                const int r   = rbase + k;
                const int hin = h0 - 1 + r;
                const bool bad = (hin < 0) || (hin > 255);
                const u32 pk = bad ? 0u : pk2(a[k], c2[k]);
                *(u32*)(ldst + r * ROWBYTES + (j << 2)) = pk;
            }
        }
    }
    __syncthreads();   // the only barrier before compute

    // ---- compute: each wave does 2 output rows, barrier-free
    #pragma unroll
    for (int i = 0; i < 2; ++i) {
        const int hr = (wave << 1) + i;                   // 0..15

        f16v acc0, acc1;
        #pragma unroll
        for (int rg = 0; rg < 16; ++rg) { acc0[rg] = 0.f; acc1[rg] = 0.f; }

        #pragma unroll
        for (int kh = 0; kh < 3; ++kh) {
            const char* rowp = lds + (hr + kh) * ROWBYTES + g * 1056 + (ln << 4);
            #pragma unroll
            for (int kw = 0; kw < 3; ++kw) {
                const int tap = kh * 3 + kw;
                #pragma unroll
                for (int q = 0; q < 2; ++q) {
                    const char* pB = rowp + q * 2112 + (kw << 4);
                    const s8v b0 = *(const s8v*)pB;           // px = w0+ln+kw-1
                    const s8v b1 = *(const s8v*)(pB + 512);   // px +32
                    acc0 = __builtin_amdgcn_mfma_f32_32x32x16_bf16(A[tap][q], b0, acc0, 0, 0, 0);
                    acc1 = __builtin_amdgcn_mfma_f32_32x32x16_bf16(A[tap][q], b1, acc1, 0, 0, 0);
                }
            }
        }

        // epilogue: D col(px)=ln, row(o)=(rg&3)+8*(rg>>2)+4*g
        const int h = h0 + hr;
        float* op = out + ((size_t)n << 21) + (size_t)h * 256 + w0 + ln;
        #pragma unroll
        for (int rg = 0; rg < 16; ++rg) {
            const int o = (rg & 3) + 8 * (rg >> 2) + 4 * g;
            op[(size_t)o * 65536]      = scale * acc0[rg] + bias_r[rg];
            op[(size_t)o * 65536 + 32] = scale * acc1[rg] + bias_r[rg];
        }
    }
}

extern "C" void kernel_launch(void* const* d_in, const int* in_sizes, int n_in,
                              void* d_out, int out_size, void* d_ws, size_t ws_size,
                              hipStream_t stream) {
    const float* x     = (const float*)d_in[0];
    const float* wgt   = (const float*)d_in[1];
    const float* bias  = (const float*)d_in[2];
    const float* scale = (const float*)d_in[3];
    float* out = (float*)d_out;
    k_fused<<<dim3(1024), dim3(512), 0, stream>>>(x, wgt, bias, scale, out);
}

// Round 15
// 56.705 us; speedup vs baseline: 1.1787x; 1.1787x over previous
//
#include <hip/hip_runtime.h>

typedef unsigned short u16;
typedef unsigned int   u32;
typedef short s8v  __attribute__((ext_vector_type(8)));   // 8 bf16 (4 VGPR)
typedef float f16v __attribute__((ext_vector_type(16)));  // 32x32 acc
typedef unsigned int u32x4 __attribute__((ext_vector_type(4)));

#define ROWBYTES 4224                 // 4 c-chunks * (66 px * 16 B)
#define NROWS    18                   // 16 output rows + 2 halo
#define LDS_BYTES (NROWS * ROWBYTES)  // 76032 -> 2 blocks/CU

__device__ inline u16 f2bf(float f) {
    u32 u = __builtin_bit_cast(u32, f);
    u += 0x7FFFu + ((u >> 16) & 1u);   // RNE; inputs finite
    return (u16)(u >> 16);
}
__device__ inline u32 pk2(float lo, float hi) {
    return (u32)f2bf(lo) | ((u32)f2bf(hi) << 16);
}

// Fused conv, R6 structure + h-major (DRAM-page-sequential) staging loads:
// each wave walks 18 rows of ONE channel back-to-back (256B segs, 1KB stride
// = same-page bursts) instead of hopping 256KB between channels per load.
// Block: 256 thr = 4 waves; owns 32o x 64w x 16h. Grid: 16n*16hs*4wb = 1024.
__global__ __launch_bounds__(256, 2) void k_fused(const float* __restrict__ x,
                                                  const float* __restrict__ wgt,
                                                  const float* __restrict__ bias,
                                                  const float* __restrict__ scale_p,
                                                  float* __restrict__ out) {
    __shared__ __align__(16) char lds[LDS_BYTES];

    // bijective XCD swizzle: 8 consecutive logical blocks -> same XCD
    const int b    = ((blockIdx.x & 7) << 7) | (blockIdx.x >> 3);   // grid 1024
    const int wb   = b & 3;
    const int hs   = (b >> 2) & 15;
    const int n    = b >> 6;
    const int w0   = wb << 6;
    const int h0   = hs << 4;
    const int t    = threadIdx.x;
    const int l    = t & 63;
    const int wave = t >> 6;
    const int g    = l >> 5;
    const int ln   = l & 31;

    // ---- weight repack into LDS overlay: [o][c][9] f32 -> [tap][o*32+c] bf16
    {
        u16* wl = (u16*)lds;
        #pragma unroll
        for (int k = 0; k < 36; ++k) {
            const int idx = t + (k << 8);
            const int tap = idx % 9;
            const int oc  = idx / 9;
            wl[tap * 1024 + oc] = f2bf(wgt[idx]);
        }
    }
    __syncthreads();

    // A frags: wt[tap][o=ln][c = q*16 + g*8 + e]
    s8v A[9][2];
    {
        const u16* wl = (const u16*)lds;
        #pragma unroll
        for (int tap = 0; tap < 9; ++tap)
            #pragma unroll
            for (int q = 0; q < 2; ++q)
                A[tap][q] = *(const s8v*)(wl + tap * 1024 + ln * 32 + q * 16 + g * 8);
    }
    const float scale = scale_p[0];
    float bias_r[16];
    #pragma unroll
    for (int rg = 0; rg < 16; ++rg) bias_r[rg] = bias[(rg & 3) + 8 * (rg >> 2) + 4 * g];
    __syncthreads();   // weight overlay free

    const float* xbase = x + ((size_t)n << 21);           // n*32*65536

    // ---- halo px (ps=0, ps=65): 144 gather threads, u32x4 writes
    if (t < 144) {
        const int cc   = t / 36;
        const int rem  = t - cc * 36;
        const int side = rem / 18;
        const int r    = rem - side * 18;
        const int hin  = h0 - 1 + r;
        const int wg   = w0 - 1 + side * 65;
        u32 q0 = 0, q1 = 0, q2 = 0, q3 = 0;
        if (hin >= 0 && hin < 256 && wg >= 0 && wg < 256) {
            const float* p = xbase + (size_t)(cc * 8) * 65536 + (size_t)hin * 256 + wg;
            q0 = pk2(p[0],      p[65536]);
            q1 = pk2(p[131072], p[196608]);
            q2 = pk2(p[262144], p[327680]);
            q3 = pk2(p[393216], p[458752]);
        }
        *(u32x4*)(lds + r * ROWBYTES + cc * 1056 + side * 1040) = u32x4{q0, q1, q2, q3};
    }

    // ---- main staging, h-major per channel-pair: wave = c-chunk (8 channels),
    // lane l -> px w0+l (ps=l+1). For each pair j: 18 page-sequential loads of
    // channel 2j, then 18 of channel 2j+1, then pack+write 18 u32s.
    {
        const float* pc = xbase + (size_t)(wave * 8) * 65536 + w0 + l;
        char* ldst = lds + wave * 1056 + ((l + 1) << 4);
        #pragma unroll
        for (int j = 0; j < 4; ++j) {
            const float* p0 = pc + (size_t)(2 * j) * 65536;
            const float* p1 = p0 + 65536;
            float a[NROWS], c2[NROWS];
            #pragma unroll
            for (int r = 0; r < NROWS; ++r) {             // channel 2j: 18 seq rows
                const int hin = h0 - 1 + r;
                const int hcl = hin < 0 ? 0 : (hin > 255 ? 255 : hin);
                a[r] = p0[(size_t)hcl * 256];
            }
            #pragma unroll
            for (int r = 0; r < NROWS; ++r) {             // channel 2j+1: 18 seq rows
                const int hin = h0 - 1 + r;
                const int hcl = hin < 0 ? 0 : (hin > 255 ? 255 : hin);
                c2[r] = p1[(size_t)hcl * 256];
            }
            #pragma unroll
            for (int r = 0; r < NROWS; ++r) {
                const int hin = h0 - 1 + r;
                const bool bad = (hin < 0) || (hin > 255);
                const u32 pk = bad ? 0u : pk2(a[r], c2[r]);
                *(u32*)(ldst + r * ROWBYTES + (j << 2)) = pk;
            }
        }
    }
    __syncthreads();   // the only barrier before compute

    // ---- compute: each wave does 4 output rows, barrier-free
    #pragma unroll
    for (int i = 0; i < 4; ++i) {
        const int hr = (wave << 2) + i;                   // 0..15

        f16v acc0, acc1;
        #pragma unroll
        for (int rg = 0; rg < 16; ++rg) { acc0[rg] = 0.f; acc1[rg] = 0.f; }

        #pragma unroll
        for (int kh = 0; kh < 3; ++kh) {
            const char* rowp = lds + (hr + kh) * ROWBYTES + g * 1056 + (ln << 4);
            #pragma unroll
            for (int kw = 0; kw < 3; ++kw) {
                const int tap = kh * 3 + kw;
                #pragma unroll
                for (int q = 0; q < 2; ++q) {
                    const char* pB = rowp + q * 2112 + (kw << 4);
                    const s8v b0 = *(const s8v*)pB;           // px = w0+ln+kw-1
                    const s8v b1 = *(const s8v*)(pB + 512);   // px +32
                    acc0 = __builtin_amdgcn_mfma_f32_32x32x16_bf16(A[tap][q], b0, acc0, 0, 0, 0);
                    acc1 = __builtin_amdgcn_mfma_f32_32x32x16_bf16(A[tap][q], b1, acc1, 0, 0, 0);
                }
            }
        }

        // epilogue: D col(px)=ln, row(o)=(rg&3)+8*(rg>>2)+4*g
        const int h = h0 + hr;
        float* op = out + ((size_t)n << 21) + (size_t)h * 256 + w0 + ln;
        #pragma unroll
        for (int rg = 0; rg < 16; ++rg) {
            const int o = (rg & 3) + 8 * (rg >> 2) + 4 * g;
            op[(size_t)o * 65536]      = scale * acc0[rg] + bias_r[rg];
            op[(size_t)o * 65536 + 32] = scale * acc1[rg] + bias_r[rg];
        }
    }
}

extern "C" void kernel_launch(void* const* d_in, const int* in_sizes, int n_in,
                              void* d_out, int out_size, void* d_ws, size_t ws_size,
                              hipStream_t stream) {
    const float* x     = (const float*)d_in[0];
    const float* wgt   = (const float*)d_in[1];
    const float* bias  = (const float*)d_in[2];
    const float* scale = (const float*)d_in[3];
    float* out = (float*)d_out;
    k_fused<<<dim3(1024), dim3(256), 0, stream>>>(x, wgt, bias, scale, out);
}